// Round 9
// baseline (275.158 us; speedup 1.0000x reference)
//
#include <hip/hip_runtime.h>

#define N_NODES 50000
#define N_EDGES 10000
#define NNZ     800000
#define C       256
#define SLOPE   0.01f
#define KTOT    50176   // node count padded to 512*98
#define KCHUNK  512     // 8 * 64
#define NZB     98      // KTOT / KCHUNK
#define MPAD    10048   // edge count padded to multiple of 64

#define NB      250     // coarse buckets per side
#define EB_E    40      // edges per bucket   (250*40  = 10000)
#define EB_N    200     // nodes per bucket   (250*200 = 50000)
#define CHUNK   3125    // NNZ / 256 blocks
#define CAP     6000    // LDS item capacity in bucket_sort (mean 3200, sd ~57)
#define MP_E    288     // per-bucket pad slack, edge side (40 rows * 7 + align 8)
#define MP_N    1408    // per-bucket pad slack, node side (200 rows * 7 + align 8)

#define EAGG_B  157     // edge-agg blocks per slice; 2 iters over 314 groups of 32 edges
#define NAGG_B  196     // node-agg blocks per slice; 2 iters over 392 group-pairs (128 nodes)

// ---- workspace layout (bytes) ----
#define OFF_CC_E    0          // 250*4 coarse counts (edge)
#define OFF_CC_N    1024       // 250*4 coarse counts (node)
#define OFF_CUR_E   2048       // 250*4 scatter cursors
#define OFF_CUR_N   3072       // 250*4
#define OFF_DEG_E   4096       // 10048*4 row degrees (edge), pad rows ZERO
#define OFF_DEG_N   45056      // 50176*4 row degrees (node), pad rows ZERO
#define ZERO_BYTES  245760     // zero region: counters + deg arrays
#define OFF_CB_E    266240     // 251*4 coarse bases (edge)
#define OFF_CB_N    267264     // 251*4 coarse bases (node)
#define OFF_RS_N    268288     // 50001*4 PADDED row starts (written by bucket_sort)
#define OFF_RS_E    468480     // 10001*4 PADDED row starts (written by bucket_sort)
#define OFF_BUF_E   508672     // 800000*4 bucketed items (edge side)
#define OFF_BUF_N   3708672    // 800000*4 bucketed items (node side)
#define OFF_CSR_E   6908672    // <=872008*2 ushort node ids, rows 8-padded w/ sentinel
#define OFF_CSR_N   10108672   // <=1152000*2 ushort edge ids, rows 8-padded w/ sentinel
#define OFF_EMBH    13308672   // SLICE-MAJOR [8][50001][32ch] bf16 incl zero row 50000
#define OFF_YT      13308672   // 256*50176*2 bf16 — ALIASES embh (embh dead before
                               // node_aggregate writes yT); ends 38,998,784
#define OFF_EACC    39000064   // 10048*256*2 bf16 row-major (dead after edge_gemm)
#define OFF_E2      44144640   // SLICE-MAJOR [8][10048][32ch] bf16; rows >=10000 ZERO
#define OFF_CWH     49289216   // 256*256*2 bf16 conv_w
#define OFF_PART    49420288   // 98*10*4096*4 gram partials -> end 65,476,608

typedef __attribute__((ext_vector_type(8))) short short8;
typedef __attribute__((ext_vector_type(4))) float floatx4;
typedef __attribute__((ext_vector_type(2))) float f32x2;

static __device__ __forceinline__ unsigned short f2bf(float f) {
    unsigned int u = __float_as_uint(f);
    u = (u + 0x7fffu + ((u >> 16) & 1u)) >> 16;   // RNE
    return (unsigned short)u;
}

// unpack uint4 (8 bf16) and accumulate into 4 packed f32x2 (v_pk_add_f32 path)
static __device__ __forceinline__ void acc_bf8p(const uint4 d, f32x2* a) {
    f32x2 v0 = { __uint_as_float(d.x << 16), __uint_as_float(d.x & 0xffff0000u) };
    f32x2 v1 = { __uint_as_float(d.y << 16), __uint_as_float(d.y & 0xffff0000u) };
    f32x2 v2 = { __uint_as_float(d.z << 16), __uint_as_float(d.z & 0xffff0000u) };
    f32x2 v3 = { __uint_as_float(d.w << 16), __uint_as_float(d.w & 0xffff0000u) };
    a[0] += v0; a[1] += v1; a[2] += v2; a[3] += v3;
}

// extract 8 ushort indices from one uint4 (16B of csr)
static __device__ __forceinline__ void idx8(const uint4 pk, int* ix) {
    ix[0] = (int)(pk.x & 0xffffu); ix[1] = (int)(pk.x >> 16);
    ix[2] = (int)(pk.y & 0xffffu); ix[3] = (int)(pk.y >> 16);
    ix[4] = (int)(pk.z & 0xffffu); ix[5] = (int)(pk.z >> 16);
    ix[6] = (int)(pk.w & 0xffffu); ix[7] = (int)(pk.w >> 16);
}

__global__ __launch_bounds__(256) void zero_kernel(float4* __restrict__ p, int n4) {
    int i = blockIdx.x * 256 + threadIdx.x;
    if (i < n4) p[i] = make_float4(0.f, 0.f, 0.f, 0.f);
}

// FUSED prep: blocks [0,6251) cast emb->bf16 SLICE-MAJOR (+ zero sentinel row),
// [6251,6283) cast conv_w->bf16, [6283,6539) coarse histogram.
#define PREP_EMB_BLOCKS 6251
#define PREP_CW_BLOCKS  32
__global__ __launch_bounds__(256) void prep_kernel(const float4* __restrict__ emb4,
                                                   uint4* __restrict__ embh4,
                                                   const float4* __restrict__ cw4,
                                                   uint4* __restrict__ cwh4,
                                                   const int* __restrict__ node_idx,
                                                   const int* __restrict__ edge_idx,
                                                   int* __restrict__ cc_e,
                                                   int* __restrict__ cc_n) {
    __shared__ int he[NB], hn[NB];
    int b = blockIdx.x, tid = threadIdx.x;
    if (b < PREP_EMB_BLOCKS) {
        int i = b * 256 + tid;
        if (i >= 1600032) return;
        uint4 o = {0u, 0u, 0u, 0u};
        if (i < 1600000) {
            float4 f0 = emb4[2 * i], f1 = emb4[2 * i + 1];
            o.x = f2bf(f0.x) | ((unsigned)f2bf(f0.y) << 16);
            o.y = f2bf(f0.z) | ((unsigned)f2bf(f0.w) << 16);
            o.z = f2bf(f1.x) | ((unsigned)f2bf(f1.y) << 16);
            o.w = f2bf(f1.z) | ((unsigned)f2bf(f1.w) << 16);
        }
        // slice-major: node = i>>5, chunk c = i&31 (8 ch each), slice = c>>2
        int node = i >> 5, c = i & 31;
        embh4[(size_t)(((c >> 2) * 50001 + node) << 2) + (c & 3)] = o;
    } else if (b < PREP_EMB_BLOCKS + PREP_CW_BLOCKS) {
        int i = (b - PREP_EMB_BLOCKS) * 256 + tid;   // < 8192
        float4 f0 = cw4[2 * i], f1 = cw4[2 * i + 1];
        uint4 o;
        o.x = f2bf(f0.x) | ((unsigned)f2bf(f0.y) << 16);
        o.y = f2bf(f0.z) | ((unsigned)f2bf(f0.w) << 16);
        o.z = f2bf(f1.x) | ((unsigned)f2bf(f1.y) << 16);
        o.w = f2bf(f1.z) | ((unsigned)f2bf(f1.w) << 16);
        cwh4[i] = o;
    } else {
        int base = (b - PREP_EMB_BLOCKS - PREP_CW_BLOCKS) * CHUNK;
        for (int i = tid; i < NB; i += 256) { he[i] = 0; hn[i] = 0; }
        __syncthreads();
        for (int i = tid; i < CHUNK; i += 256) {
            atomicAdd(&he[edge_idx[base + i] / EB_E], 1);
            atomicAdd(&hn[node_idx[base + i] / EB_N], 1);
        }
        __syncthreads();
        for (int k = tid; k < NB; k += 256) {
            if (he[k]) atomicAdd(&cc_e[k], he[k]);
            if (hn[k]) atomicAdd(&cc_n[k], hn[k]);
        }
    }
}

// single-block exclusive scan of both coarse-count arrays -> coarse bases
__global__ __launch_bounds__(256) void coarse_scan_kernel(const int* __restrict__ cc_e,
                                                          const int* __restrict__ cc_n,
                                                          int* __restrict__ cb_e,
                                                          int* __restrict__ cb_n) {
    __shared__ int tmp[256];
    int tid = threadIdx.x;
    int v = (tid < NB) ? cc_e[tid] : 0;
    tmp[tid] = v;
    __syncthreads();
    for (int off = 1; off < 256; off <<= 1) {
        int t = (tid >= off) ? tmp[tid - off] : 0;
        __syncthreads();
        tmp[tid] += t;
        __syncthreads();
    }
    if (tid < NB) cb_e[tid + 1] = tmp[tid];
    if (tid == 0) cb_e[0] = 0;
    __syncthreads();
    v = (tid < NB) ? cc_n[tid] : 0;
    tmp[tid] = v;
    __syncthreads();
    for (int off = 1; off < 256; off <<= 1) {
        int t = (tid >= off) ? tmp[tid - off] : 0;
        __syncthreads();
        tmp[tid] += t;
        __syncthreads();
    }
    if (tid < NB) cb_n[tid + 1] = tmp[tid];
    if (tid == 0) cb_n[0] = 0;
}

// pass 1: scatter into coarse buckets. Single LDS-hist pass: the pass-1
// atomicAdd return value IS the local offset — carried in registers.
__global__ __launch_bounds__(256) void bucket_scatter_kernel(const int* __restrict__ node_idx,
                                                             const int* __restrict__ edge_idx,
                                                             const int* __restrict__ cb_e,
                                                             const int* __restrict__ cb_n,
                                                             int* __restrict__ cur_e,
                                                             int* __restrict__ cur_n,
                                                             int* __restrict__ buf_e,
                                                             int* __restrict__ buf_n) {
    __shared__ int he[NB], hn[NB], be[NB], bn[NB];
    int tid = threadIdx.x;
    int base = blockIdx.x * CHUNK;
    for (int i = tid; i < NB; i += 256) { he[i] = 0; hn[i] = 0; }
    __syncthreads();
    int pe[13], pn[13];   // (bucket<<12) | local_offset ; offset < 3125 < 4096
    #pragma unroll
    for (int k = 0; k < 13; k++) {
        int i = tid + k * 256;
        if (i < CHUNK) {
            int e = edge_idx[base + i], v = node_idx[base + i];
            int ke = e / EB_E, kn = v / EB_N;
            pe[k] = (ke << 12) | atomicAdd(&he[ke], 1);
            pn[k] = (kn << 12) | atomicAdd(&hn[kn], 1);
        }
    }
    __syncthreads();
    for (int k = tid; k < NB; k += 256) {
        int c = he[k];
        be[k] = cb_e[k] + (c ? atomicAdd(&cur_e[k], c) : 0);
        int cn = hn[k];
        bn[k] = cb_n[k] + (cn ? atomicAdd(&cur_n[k], cn) : 0);
    }
    __syncthreads();
    #pragma unroll
    for (int k = 0; k < 13; k++) {
        int i = tid + k * 256;
        if (i < CHUNK) {
            int e = edge_idx[base + i], v = node_idx[base + i];
            int ke = pe[k] >> 12, oe = pe[k] & 4095;
            buf_e[be[ke] + oe] = (v << 6) | (e - ke * EB_E);
            int kn = pn[k] >> 12, on = pn[k] & 4095;
            buf_n[bn[kn] + on] = (e << 8) | (v - kn * EB_N);
        }
    }
}

// pass 2: per-bucket LDS counting sort -> PADDED CSR (rows 8-aligned, padded
// to multiple of 8 with zero-sentinel ids) + padded row starts rs + deg array.
__global__ __launch_bounds__(256) void bucket_sort_kernel(const int* __restrict__ buf_e,
                                                          const int* __restrict__ buf_n,
                                                          const int* __restrict__ cb_e,
                                                          const int* __restrict__ cb_n,
                                                          unsigned short* __restrict__ csr_e,
                                                          unsigned short* __restrict__ csr_n,
                                                          int* __restrict__ rs_e,
                                                          int* __restrict__ rs_n,
                                                          int* __restrict__ deg_e,
                                                          int* __restrict__ deg_n) {
    __shared__ int A[CAP];
    __shared__ int h[EB_N], bs[EB_N], cs[EB_N];
    int tid = threadIdx.x;
    bool edgeSide = blockIdx.x < NB;
    int k = edgeSide ? blockIdx.x : blockIdx.x - NB;
    int eb = edgeSide ? EB_E : EB_N;
    int shift = edgeSide ? 6 : 8;
    int mask = (1 << shift) - 1;
    int mp = edgeSide ? MP_E : MP_N;
    int sent = edgeSide ? N_NODES : N_EDGES;
    const int* cb  = edgeSide ? cb_e : cb_n;
    const int* buf = edgeSide ? buf_e : buf_n;
    unsigned short* csr = edgeSide ? csr_e : csr_n;
    int* rs  = edgeSide ? rs_e : rs_n;
    int* deg = edgeSide ? deg_e : deg_n;
    int base = cb[k];                               // exact base (buf reads)
    int base_pad = (base + k * mp + 7) & ~7;        // 8-aligned padded base (csr writes)
    int cnt = cb[k + 1] - base;
    for (int i = tid; i < eb; i += 256) h[i] = 0;
    __syncthreads();
    for (int i = tid; i < cnt; i += 256) {
        int it = buf[base + i];
        if (i < CAP) A[i] = it;
        atomicAdd(&h[it & mask], 1);
    }
    __syncthreads();
    if (tid == 0) {
        int s = 0;
        for (int j = 0; j < eb; j++) { bs[j] = s; s += (h[j] + 7) & ~7; }
    }
    __syncthreads();
    for (int j = tid; j < eb; j += 256) {
        rs[k * eb + j] = base_pad + bs[j];
        deg[k * eb + j] = h[j];
        cs[j] = h[j];
        h[j] = 0;
    }
    if (tid == 0 && k == NB - 1) rs[edgeSide ? N_EDGES : N_NODES] = NNZ;
    __syncthreads();
    // fill pad slots with sentinel (disjoint from scatter slots)
    for (int j = tid; j < eb; j += 256) {
        int c0 = cs[j], e0 = (c0 + 7) & ~7;
        for (int x = c0; x < e0; x++) csr[base_pad + bs[j] + x] = (unsigned short)sent;
    }
    for (int i = tid; i < cnt; i += 256) {
        int it = (i < CAP) ? A[i] : buf[base + i];
        int loc = it & mask;
        int off = bs[loc] + atomicAdd(&h[loc], 1);
        csr[base_pad + off] = (unsigned short)(it >> shift);
    }
}

// XCD-sliced edge aggregation, DUAL-EDGE per 16-lane group: each quad runs
// both edges' chunk sub-streams (2 independent load chains -> 2x MLP).
// Rows 8-padded with sentinel -> unconditional unpack. 2-stage shfl reduce;
// q==0 stores e0, q==1 stores e1. Slice table 3.2MB, L2-resident per XCD.
__global__ __launch_bounds__(256) void edge_aggregate_kernel(const uint4* __restrict__ embh4,
                                                             const unsigned short* __restrict__ csr_e,
                                                             const int* __restrict__ rs_e,
                                                             const int* __restrict__ deg_e,
                                                             unsigned short* __restrict__ e_acc_h) {
    int sid = blockIdx.x & 7, b = blockIdx.x >> 3;
    const uint4* __restrict__ csr4 = (const uint4*)csr_e;
    int tid = threadIdx.x;
    int w = tid >> 6, lane = tid & 63;
    int grp = lane >> 4, q = (lane >> 2) & 3, c4 = lane & 3;
    const uint4* __restrict__ tbl = embh4 + (size_t)sid * 50001 * 4 + c4;
    for (int gg = b; gg < 314; gg += EAGG_B) {
        int e0 = gg * 32 + w * 8 + grp * 2;         // < MPAD (314*32 = 10048)
        int e1 = e0 + 1;
        int s0 = rs_e[min(e0, N_EDGES)], d0 = deg_e[e0];
        int s1 = rs_e[min(e1, N_EDGES)], d1 = deg_e[e1];
        int c00 = s0 >> 3, nc0 = (d0 + 7) >> 3;
        int c01 = s1 >> 3, nc1 = (d1 + 7) >> 3;
        f32x2 aA[4] = {}, aB[4] = {};
        int m = max(nc0, nc1);
        for (int c = q; c < m; c += 4) {
            if (c < nc0) {
                uint4 pk = csr4[c00 + c];
                int ix[8];
                idx8(pk, ix);
                #pragma unroll
                for (int j = 0; j < 8; j++) acc_bf8p(tbl[(size_t)ix[j] * 4], aA);
            }
            if (c < nc1) {
                uint4 pk = csr4[c01 + c];
                int ix[8];
                idx8(pk, ix);
                #pragma unroll
                for (int j = 0; j < 8; j++) acc_bf8p(tbl[(size_t)ix[j] * 4], aB);
            }
        }
        #pragma unroll
        for (int off = 4; off <= 8; off <<= 1) {
            #pragma unroll
            for (int j = 0; j < 4; j++) {
                aA[j].x += __shfl_xor(aA[j].x, off); aA[j].y += __shfl_xor(aA[j].y, off);
                aB[j].x += __shfl_xor(aB[j].x, off); aB[j].y += __shfl_xor(aB[j].y, off);
            }
        }
        if (q == 0) {
            uint4 o;
            o.x = f2bf(aA[0].x) | ((unsigned)f2bf(aA[0].y) << 16);
            o.y = f2bf(aA[1].x) | ((unsigned)f2bf(aA[1].y) << 16);
            o.z = f2bf(aA[2].x) | ((unsigned)f2bf(aA[2].y) << 16);
            o.w = f2bf(aA[3].x) | ((unsigned)f2bf(aA[3].y) << 16);
            ((uint4*)(e_acc_h + (size_t)e0 * C + sid * 32))[c4] = o;
        }
        if (q == 1) {
            uint4 o;
            o.x = f2bf(aB[0].x) | ((unsigned)f2bf(aB[0].y) << 16);
            o.y = f2bf(aB[1].x) | ((unsigned)f2bf(aB[1].y) << 16);
            o.z = f2bf(aB[2].x) | ((unsigned)f2bf(aB[2].y) << 16);
            o.w = f2bf(aB[3].x) | ((unsigned)f2bf(aB[3].y) << 16);
            ((uint4*)(e_acc_h + (size_t)e1 * C + sid * 32))[c4] = o;
        }
    }
}

// e2[m][n] = Binv[m] * sum_k e_acc[m][k] * conv_w[n][k] via MFMA; grid (157,4)
// output stored SLICE-MAJOR [8][MPAD][32]; pad rows (m >= N_EDGES) ZERO
__global__ __launch_bounds__(256) void edge_gemm_mfma_kernel(const unsigned short* __restrict__ e_acc_h,
                                                             const unsigned short* __restrict__ cwh,
                                                             const int* __restrict__ deg_e,
                                                             unsigned short* __restrict__ e2h) {
    __shared__ __align__(16) unsigned short As[64 * 72];
    __shared__ __align__(16) unsigned short Bs[64 * 72];
    int i0 = blockIdx.x * 64, j0 = blockIdx.y * 64;
    int tid = threadIdx.x;
    int w = tid >> 6, lane = tid & 63;
    int col = lane & 15, quad = lane >> 4;
    floatx4 acc[4] = {};
    for (int step = 0; step < 4; step++) {
        int kb = step * 64;
        __syncthreads();
        #pragma unroll
        for (int l = 0; l < 2; l++) {
            int slot = tid + l * 256;
            int row = slot >> 3, grp = slot & 7;
            uint4 da = *(const uint4*)(e_acc_h + (size_t)(i0 + row) * C + kb + grp * 8);
            *(uint4*)(&As[row * 72 + grp * 8]) = da;
            uint4 db = *(const uint4*)(cwh + (size_t)(j0 + row) * C + kb + grp * 8);
            *(uint4*)(&Bs[row * 72 + grp * 8]) = db;
        }
        __syncthreads();
        #pragma unroll
        for (int sub = 0; sub < 2; sub++) {
            short8 a = *(const short8*)(&As[(w * 16 + col) * 72 + sub * 32 + quad * 8]);
            #pragma unroll
            for (int jt = 0; jt < 4; jt++) {
                short8 b = *(const short8*)(&Bs[(jt * 16 + col) * 72 + sub * 32 + quad * 8]);
                acc[jt] = __builtin_amdgcn_mfma_f32_16x16x32_bf16(a, b, acc[jt], 0, 0, 0);
            }
        }
    }
    #pragma unroll
    for (int r = 0; r < 4; r++) {
        int m = i0 + w * 16 + quad * 4 + r;          // < MPAD always
        int dg = deg_e[m];                           // pad rows: 0
        float binv = (dg > 0) ? 1.0f / (float)dg : 0.0f;
        #pragma unroll
        for (int jt = 0; jt < 4; jt++) {
            int ch = j0 + jt * 16 + col;
            e2h[(size_t)((ch >> 5) * MPAD + m) * 32 + (ch & 31)] = f2bf(acc[jt][r] * binv);
        }
    }
}

// XCD-sliced node aggregation, DUAL-NODE per quad: each quad processes two
// nodes (paired groups) with interleaved chunk loops -> 2 independent load
// chains. Unconditional unpack (rows 8-padded). Fused Dinv/bias/lrelu;
// LDS transpose (two groups) -> 16B yT stores. Table 0.64MB, L2-resident.
__global__ __launch_bounds__(256) void node_aggregate_t_kernel(const uint4* __restrict__ e2h4,
                                                               const unsigned short* __restrict__ csr_n,
                                                               const int* __restrict__ rs_n,
                                                               const int* __restrict__ deg_n,
                                                               const float* __restrict__ conv_b,
                                                               unsigned short* __restrict__ yT) {
    __shared__ unsigned short T[2][32][66];   // [group][slice-ch][node-local]
    int sid = blockIdx.x & 7, b = blockIdx.x >> 3;
    const uint4* __restrict__ csr4 = (const uint4*)csr_n;
    int tid = threadIdx.x;
    int w = tid >> 6, lane = tid & 63;
    int q = lane >> 2, c4 = lane & 3;
    const uint4* __restrict__ tbl = e2h4 + (size_t)sid * MPAD * 4 + c4;
    float4 b0 = ((const float4*)conv_b)[sid * 8 + c4 * 2];
    float4 b1 = ((const float4*)conv_b)[sid * 8 + c4 * 2 + 1];
    float bb[8] = {b0.x, b0.y, b0.z, b0.w, b1.x, b1.y, b1.z, b1.w};
    for (int p = b; p < 392; p += NAGG_B) {
        int nA = p * 128 + w * 16 + q;              // group 2p
        int nB = nA + 64;                           // group 2p+1 (< KTOT)
        int sA = rs_n[min(nA, N_NODES)], dA = deg_n[nA];
        int sB = rs_n[min(nB, N_NODES)], dB = deg_n[nB];
        int cA = sA >> 3, ncA = (dA + 7) >> 3;
        int cB = sB >> 3, ncB = (dB + 7) >> 3;
        f32x2 aA[4] = {}, aB[4] = {};
        int m = max(ncA, ncB);
        for (int c = 0; c < m; c++) {
            if (c < ncA) {
                uint4 pk = csr4[cA + c];
                int ix[8];
                idx8(pk, ix);
                #pragma unroll
                for (int j = 0; j < 8; j++) acc_bf8p(tbl[(size_t)ix[j] * 4], aA);
            }
            if (c < ncB) {
                uint4 pk = csr4[cB + c];
                int ix[8];
                idx8(pk, ix);
                #pragma unroll
                for (int j = 0; j < 8; j++) acc_bf8p(tbl[(size_t)ix[j] * 4], aB);
            }
        }
        float dinvA = (dA > 0) ? 1.0f / (float)dA : 0.0f;
        float dinvB = (dB > 0) ? 1.0f / (float)dB : 0.0f;
        #pragma unroll
        for (int j = 0; j < 4; j++) {
            float r0 = aA[j].x * dinvA + bb[2 * j];
            float r1 = aA[j].y * dinvA + bb[2 * j + 1];
            r0 = (r0 > 0.f) ? r0 : SLOPE * r0;
            r1 = (r1 > 0.f) ? r1 : SLOPE * r1;
            if (nA >= N_NODES) { r0 = 0.f; r1 = 0.f; }   // zero-pad rows for gram
            T[0][c4 * 8 + 2 * j][w * 16 + q] = f2bf(r0);
            T[0][c4 * 8 + 2 * j + 1][w * 16 + q] = f2bf(r1);
            float r2 = aB[j].x * dinvB + bb[2 * j];
            float r3 = aB[j].y * dinvB + bb[2 * j + 1];
            r2 = (r2 > 0.f) ? r2 : SLOPE * r2;
            r3 = (r3 > 0.f) ? r3 : SLOPE * r3;
            if (nB >= N_NODES) { r2 = 0.f; r3 = 0.f; }
            T[1][c4 * 8 + 2 * j][w * 16 + q] = f2bf(r2);
            T[1][c4 * 8 + 2 * j + 1][w * 16 + q] = f2bf(r3);
        }
        __syncthreads();
        int rr = tid >> 3, cc = tid & 7;
        uint4 o;
        o.x = T[0][rr][cc * 8 + 0] | ((unsigned)T[0][rr][cc * 8 + 1] << 16);
        o.y = T[0][rr][cc * 8 + 2] | ((unsigned)T[0][rr][cc * 8 + 3] << 16);
        o.z = T[0][rr][cc * 8 + 4] | ((unsigned)T[0][rr][cc * 8 + 5] << 16);
        o.w = T[0][rr][cc * 8 + 6] | ((unsigned)T[0][rr][cc * 8 + 7] << 16);
        *(uint4*)(yT + (size_t)(sid * 32 + rr) * KTOT + p * 128 + cc * 8) = o;
        uint4 o2;
        o2.x = T[1][rr][cc * 8 + 0] | ((unsigned)T[1][rr][cc * 8 + 1] << 16);
        o2.y = T[1][rr][cc * 8 + 2] | ((unsigned)T[1][rr][cc * 8 + 3] << 16);
        o2.z = T[1][rr][cc * 8 + 4] | ((unsigned)T[1][rr][cc * 8 + 5] << 16);
        o2.w = T[1][rr][cc * 8 + 6] | ((unsigned)T[1][rr][cc * 8 + 7] << 16);
        *(uint4*)(yT + (size_t)(sid * 32 + rr) * KTOT + p * 128 + 64 + cc * 8) = o2;
        __syncthreads();   // protect T before next iteration's writes
    }
}

// Gram partials via MFMA, symmetry-aware (10 upper-tri tile pairs), NO atomics.
__global__ __launch_bounds__(256) void gram_mfma_kernel(const unsigned short* __restrict__ yT,
                                                        float* __restrict__ part) {
    static const int PI[10] = {0, 0, 0, 0, 1, 1, 1, 2, 2, 3};
    static const int PJ[10] = {0, 1, 2, 3, 1, 2, 3, 2, 3, 3};
    __shared__ __align__(16) unsigned short As[64 * 72];  // [col][k], stride 72
    __shared__ __align__(16) unsigned short Bs[64 * 72];
    int i0 = PI[blockIdx.x] * 64, j0 = PJ[blockIdx.x] * 64;
    bool diag = (i0 == j0);
    int kb0 = blockIdx.y * KCHUNK;
    int tid = threadIdx.x;
    int w = tid >> 6, lane = tid & 63;
    int col = lane & 15, quad = lane >> 4;
    floatx4 acc[4] = {};
    for (int step = 0; step < KCHUNK / 64; step++) {
        int kb = kb0 + step * 64;
        __syncthreads();
        #pragma unroll
        for (int l = 0; l < 2; l++) {
            int slot = tid + l * 256;
            int row = slot >> 3, grp = slot & 7;
            uint4 da = *(const uint4*)(yT + (size_t)(i0 + row) * KTOT + kb + grp * 8);
            *(uint4*)(&As[row * 72 + grp * 8]) = da;
            if (!diag) {
                uint4 db = *(const uint4*)(yT + (size_t)(j0 + row) * KTOT + kb + grp * 8);
                *(uint4*)(&Bs[row * 72 + grp * 8]) = db;
            }
        }
        __syncthreads();
        const unsigned short* Bb = diag ? As : Bs;
        #pragma unroll
        for (int sub = 0; sub < 2; sub++) {
            short8 a = *(const short8*)(&As[(w * 16 + col) * 72 + sub * 32 + quad * 8]);
            #pragma unroll
            for (int jt = 0; jt < 4; jt++) {
                short8 b = *(const short8*)(&Bb[(jt * 16 + col) * 72 + sub * 32 + quad * 8]);
                acc[jt] = __builtin_amdgcn_mfma_f32_16x16x32_bf16(a, b, acc[jt], 0, 0, 0);
            }
        }
    }
    float* slab = part + ((size_t)blockIdx.y * 10 + blockIdx.x) * 4096;
    #pragma unroll
    for (int jt = 0; jt < 4; jt++)
        #pragma unroll
        for (int r = 0; r < 4; r++)
            slab[(w * 16 + quad * 4 + r) * 64 + jt * 16 + col] = acc[jt][r];
}

// FUSED: block i reduces g row i from the 98 partial slabs (with symmetric
// mirror) into LDS, then computes out row i = lrelu(g_row @ lin_w^T + lin_b).
__global__ __launch_bounds__(256) void greduce_out_kernel(const float* __restrict__ part,
                                                          const float* __restrict__ lin_w,
                                                          const float* __restrict__ lin_b,
                                                          float* __restrict__ out) {
    __shared__ float gs[C];
    int i = blockIdx.x, j = threadIdx.x;
    int a = i >> 6, b = j >> 6;
    int lo = min(a, b), hi = max(a, b);
    int t = lo * (7 - lo) / 2 + hi;          // pair index in PI/PJ order
    int li = (a <= b) ? (i & 63) : (j & 63);
    int lj = (a <= b) ? (j & 63) : (i & 63);
    const float* p = part + (size_t)t * 4096 + li * 64 + lj;
    float s = 0.f;
    for (int z = 0; z < NZB; z++) s += p[(size_t)z * 40960];
    gs[j] = s;
    __syncthreads();
    float acc = lin_b[j];
    const float* wrow = lin_w + (size_t)j * C;
    for (int k = 0; k < C; k++) acc += gs[k] * wrow[k];
    out[(size_t)i * C + j] = (acc > 0.f) ? acc : SLOPE * acc;
}

extern "C" void kernel_launch(void* const* d_in, const int* in_sizes, int n_in,
                              void* d_out, int out_size, void* d_ws, size_t ws_size,
                              hipStream_t stream) {
    const float* emb    = (const float*)d_in[0];
    const float* conv_w = (const float*)d_in[1];
    const float* conv_b = (const float*)d_in[2];
    const float* lin_w  = (const float*)d_in[3];
    const float* lin_b  = (const float*)d_in[4];
    const int*   eidx   = (const int*)d_in[5];
    const int* node_idx = eidx;        // edge_index[0]
    const int* edge_idx = eidx + NNZ;  // edge_index[1]

    char* ws = (char*)d_ws;
    int* cc_e  = (int*)(ws + OFF_CC_E);
    int* cc_n  = (int*)(ws + OFF_CC_N);
    int* cur_e = (int*)(ws + OFF_CUR_E);
    int* cur_n = (int*)(ws + OFF_CUR_N);
    int* deg_e = (int*)(ws + OFF_DEG_E);
    int* deg_n = (int*)(ws + OFF_DEG_N);
    int* cb_e  = (int*)(ws + OFF_CB_E);
    int* cb_n  = (int*)(ws + OFF_CB_N);
    int* rs_n  = (int*)(ws + OFF_RS_N);
    int* rs_e  = (int*)(ws + OFF_RS_E);
    int* buf_e = (int*)(ws + OFF_BUF_E);
    int* buf_n = (int*)(ws + OFF_BUF_N);
    unsigned short* csr_e = (unsigned short*)(ws + OFF_CSR_E);
    unsigned short* csr_n = (unsigned short*)(ws + OFF_CSR_N);
    uint4* embh4 = (uint4*)(ws + OFF_EMBH);
    unsigned short* e_acc_h = (unsigned short*)(ws + OFF_EACC);
    unsigned short* e2h = (unsigned short*)(ws + OFF_E2);
    unsigned short* cwh = (unsigned short*)(ws + OFF_CWH);
    unsigned short* yT  = (unsigned short*)(ws + OFF_YT);
    float* part = (float*)(ws + OFF_PART);
    float* out = (float*)d_out;

    zero_kernel<<<ZERO_BYTES / 4096, 256, 0, stream>>>((float4*)ws, ZERO_BYTES / 16);

    prep_kernel<<<PREP_EMB_BLOCKS + PREP_CW_BLOCKS + 256, 256, 0, stream>>>(
        (const float4*)emb, embh4, (const float4*)conv_w, (uint4*)cwh,
        node_idx, edge_idx, cc_e, cc_n);

    coarse_scan_kernel<<<1, 256, 0, stream>>>(cc_e, cc_n, cb_e, cb_n);

    bucket_scatter_kernel<<<256, 256, 0, stream>>>(node_idx, edge_idx, cb_e, cb_n,
                                                   cur_e, cur_n, buf_e, buf_n);

    bucket_sort_kernel<<<2 * NB, 256, 0, stream>>>(buf_e, buf_n, cb_e, cb_n,
                                                   csr_e, csr_n, rs_e, rs_n,
                                                   deg_e, deg_n);

    edge_aggregate_kernel<<<8 * EAGG_B, 256, 0, stream>>>(embh4, csr_e, rs_e, deg_e, e_acc_h);

    edge_gemm_mfma_kernel<<<dim3(MPAD / 64, C / 64), 256, 0, stream>>>(e_acc_h, cwh, deg_e, e2h);

    node_aggregate_t_kernel<<<8 * NAGG_B, 256, 0, stream>>>((const uint4*)e2h, csr_n, rs_n,
                                                            deg_n, conv_b, yT);

    gram_mfma_kernel<<<dim3(10, NZB), 256, 0, stream>>>(yT, part);

    greduce_out_kernel<<<C, 256, 0, stream>>>(part, lin_w, lin_b, out);
}

// Round 10
// 261.123 us; speedup vs baseline: 1.0537x; 1.0537x over previous
//
#include <hip/hip_runtime.h>

#define N_NODES 50000
#define N_EDGES 10000
#define NNZ     800000
#define C       256
#define SLOPE   0.01f
#define KTOT    50176   // node count padded to 512*98
#define KCHUNK  512     // 8 * 64
#define NZB     98      // KTOT / KCHUNK
#define MPAD    10048   // edge count padded to multiple of 64

#define NB      250     // coarse buckets per side
#define EB_E    40      // edges per bucket   (250*40  = 10000)
#define EB_N    200     // nodes per bucket   (250*200 = 50000)
#define CHUNK   3125    // NNZ / 256 blocks
#define CAP     6000    // LDS item capacity in bucket_sort (mean 3200, sd ~57)
#define MP_E    288     // per-bucket pad slack, edge side (40 rows * 7 + align 8)
#define MP_N    1408    // per-bucket pad slack, node side (200 rows * 7 + align 8)

#define EAGG_G  628     // edge-agg blocks per slice (628*16 = 10048 = MPAD), 8 slices
#define NAGG_G  1568    // node-agg blocks per slice (1568*32 = 50176 = KTOT), 4 slices

// ---- workspace layout (bytes) ----
#define OFF_CC_E    0          // 250*4 coarse counts (edge)
#define OFF_CC_N    1024       // 250*4 coarse counts (node)
#define OFF_CUR_E   2048       // 250*4 scatter cursors
#define OFF_CUR_N   3072       // 250*4
#define OFF_DEG_E   4096       // 10048*4 row degrees (edge), pad rows ZERO
#define OFF_DEG_N   45056      // 50176*4 row degrees (node), pad rows ZERO
#define ZERO_BYTES  245760     // zero region: counters + deg arrays
#define OFF_CB_E    266240     // 251*4 coarse bases (edge)
#define OFF_CB_N    267264     // 251*4 coarse bases (node)
#define OFF_RS_N    268288     // 50001*4 PADDED row starts (written by bucket_sort)
#define OFF_RS_E    468480     // 10001*4 PADDED row starts (written by bucket_sort)
#define OFF_BUF_E   508672     // 800000*4 bucketed items (edge side)
#define OFF_BUF_N   3708672    // 800000*4 bucketed items (node side)
#define OFF_CSR_E   6908672    // <=872008*2 ushort node ids, rows 8-padded w/ sentinel
#define OFF_CSR_N   10108672   // <=1152000*2 ushort edge ids, rows 8-padded w/ sentinel
#define OFF_EMBH    13308672   // SLICE-MAJOR [8][50001][32ch] bf16 incl zero row 50000
#define OFF_YT      13308672   // 256*50176*2 bf16 — ALIASES embh (embh dead before
                               // node_aggregate writes yT); ends 38,998,784
#define OFF_EACC    39000064   // 10048*256*2 bf16 row-major (dead after edge_gemm)
#define OFF_E2      44144640   // SLICE-MAJOR [4][10048][64ch] bf16; rows >=10000 ZERO
#define OFF_CWH     49289216   // 256*256*2 bf16 conv_w
#define OFF_PART    49420288   // 98*10*4096*4 gram partials -> end 65,476,608

typedef __attribute__((ext_vector_type(8))) short short8;
typedef __attribute__((ext_vector_type(4))) float floatx4;

static __device__ __forceinline__ unsigned short f2bf(float f) {
    unsigned int u = __float_as_uint(f);
    u = (u + 0x7fffu + ((u >> 16) & 1u)) >> 16;   // RNE
    return (unsigned short)u;
}

// unpack uint4 (8 bf16) and accumulate into a[0..7]
static __device__ __forceinline__ void acc_bf8(const uint4 d, float* a) {
    a[0] += __uint_as_float(d.x << 16);
    a[1] += __uint_as_float(d.x & 0xffff0000u);
    a[2] += __uint_as_float(d.y << 16);
    a[3] += __uint_as_float(d.y & 0xffff0000u);
    a[4] += __uint_as_float(d.z << 16);
    a[5] += __uint_as_float(d.z & 0xffff0000u);
    a[6] += __uint_as_float(d.w << 16);
    a[7] += __uint_as_float(d.w & 0xffff0000u);
}

// extract 8 ushort indices from one uint4 (16B of csr)
static __device__ __forceinline__ void idx8(const uint4 pk, int* ix) {
    ix[0] = (int)(pk.x & 0xffffu); ix[1] = (int)(pk.x >> 16);
    ix[2] = (int)(pk.y & 0xffffu); ix[3] = (int)(pk.y >> 16);
    ix[4] = (int)(pk.z & 0xffffu); ix[5] = (int)(pk.z >> 16);
    ix[6] = (int)(pk.w & 0xffffu); ix[7] = (int)(pk.w >> 16);
}

__global__ __launch_bounds__(256) void zero_kernel(float4* __restrict__ p, int n4) {
    int i = blockIdx.x * 256 + threadIdx.x;
    if (i < n4) p[i] = make_float4(0.f, 0.f, 0.f, 0.f);
}

// FUSED prep: blocks [0,6251) cast emb->bf16 SLICE-MAJOR (+ zero sentinel row),
// [6251,6283) cast conv_w->bf16, [6283,6539) coarse histogram.
#define PREP_EMB_BLOCKS 6251
#define PREP_CW_BLOCKS  32
__global__ __launch_bounds__(256) void prep_kernel(const float4* __restrict__ emb4,
                                                   uint4* __restrict__ embh4,
                                                   const float4* __restrict__ cw4,
                                                   uint4* __restrict__ cwh4,
                                                   const int* __restrict__ node_idx,
                                                   const int* __restrict__ edge_idx,
                                                   int* __restrict__ cc_e,
                                                   int* __restrict__ cc_n) {
    __shared__ int he[NB], hn[NB];
    int b = blockIdx.x, tid = threadIdx.x;
    if (b < PREP_EMB_BLOCKS) {
        int i = b * 256 + tid;
        if (i >= 1600032) return;
        uint4 o = {0u, 0u, 0u, 0u};
        if (i < 1600000) {
            float4 f0 = emb4[2 * i], f1 = emb4[2 * i + 1];
            o.x = f2bf(f0.x) | ((unsigned)f2bf(f0.y) << 16);
            o.y = f2bf(f0.z) | ((unsigned)f2bf(f0.w) << 16);
            o.z = f2bf(f1.x) | ((unsigned)f2bf(f1.y) << 16);
            o.w = f2bf(f1.z) | ((unsigned)f2bf(f1.w) << 16);
        }
        // slice-major: node = i>>5, chunk c = i&31 (8 ch each), slice = c>>2
        int node = i >> 5, c = i & 31;
        embh4[(size_t)(((c >> 2) * 50001 + node) << 2) + (c & 3)] = o;
    } else if (b < PREP_EMB_BLOCKS + PREP_CW_BLOCKS) {
        int i = (b - PREP_EMB_BLOCKS) * 256 + tid;   // < 8192
        float4 f0 = cw4[2 * i], f1 = cw4[2 * i + 1];
        uint4 o;
        o.x = f2bf(f0.x) | ((unsigned)f2bf(f0.y) << 16);
        o.y = f2bf(f0.z) | ((unsigned)f2bf(f0.w) << 16);
        o.z = f2bf(f1.x) | ((unsigned)f2bf(f1.y) << 16);
        o.w = f2bf(f1.z) | ((unsigned)f2bf(f1.w) << 16);
        cwh4[i] = o;
    } else {
        int base = (b - PREP_EMB_BLOCKS - PREP_CW_BLOCKS) * CHUNK;
        for (int i = tid; i < NB; i += 256) { he[i] = 0; hn[i] = 0; }
        __syncthreads();
        for (int i = tid; i < CHUNK; i += 256) {
            atomicAdd(&he[edge_idx[base + i] / EB_E], 1);
            atomicAdd(&hn[node_idx[base + i] / EB_N], 1);
        }
        __syncthreads();
        for (int k = tid; k < NB; k += 256) {
            if (he[k]) atomicAdd(&cc_e[k], he[k]);
            if (hn[k]) atomicAdd(&cc_n[k], hn[k]);
        }
    }
}

// single-block exclusive scan of both coarse-count arrays -> coarse bases
__global__ __launch_bounds__(256) void coarse_scan_kernel(const int* __restrict__ cc_e,
                                                          const int* __restrict__ cc_n,
                                                          int* __restrict__ cb_e,
                                                          int* __restrict__ cb_n) {
    __shared__ int tmp[256];
    int tid = threadIdx.x;
    int v = (tid < NB) ? cc_e[tid] : 0;
    tmp[tid] = v;
    __syncthreads();
    for (int off = 1; off < 256; off <<= 1) {
        int t = (tid >= off) ? tmp[tid - off] : 0;
        __syncthreads();
        tmp[tid] += t;
        __syncthreads();
    }
    if (tid < NB) cb_e[tid + 1] = tmp[tid];
    if (tid == 0) cb_e[0] = 0;
    __syncthreads();
    v = (tid < NB) ? cc_n[tid] : 0;
    tmp[tid] = v;
    __syncthreads();
    for (int off = 1; off < 256; off <<= 1) {
        int t = (tid >= off) ? tmp[tid - off] : 0;
        __syncthreads();
        tmp[tid] += t;
        __syncthreads();
    }
    if (tid < NB) cb_n[tid + 1] = tmp[tid];
    if (tid == 0) cb_n[0] = 0;
}

// pass 1: scatter into coarse buckets. Single LDS-hist pass: the pass-1
// atomicAdd return value IS the local offset — carried in registers.
__global__ __launch_bounds__(256) void bucket_scatter_kernel(const int* __restrict__ node_idx,
                                                             const int* __restrict__ edge_idx,
                                                             const int* __restrict__ cb_e,
                                                             const int* __restrict__ cb_n,
                                                             int* __restrict__ cur_e,
                                                             int* __restrict__ cur_n,
                                                             int* __restrict__ buf_e,
                                                             int* __restrict__ buf_n) {
    __shared__ int he[NB], hn[NB], be[NB], bn[NB];
    int tid = threadIdx.x;
    int base = blockIdx.x * CHUNK;
    for (int i = tid; i < NB; i += 256) { he[i] = 0; hn[i] = 0; }
    __syncthreads();
    int pe[13], pn[13];   // (bucket<<12) | local_offset ; offset < 3125 < 4096
    #pragma unroll
    for (int k = 0; k < 13; k++) {
        int i = tid + k * 256;
        if (i < CHUNK) {
            int e = edge_idx[base + i], v = node_idx[base + i];
            int ke = e / EB_E, kn = v / EB_N;
            pe[k] = (ke << 12) | atomicAdd(&he[ke], 1);
            pn[k] = (kn << 12) | atomicAdd(&hn[kn], 1);
        }
    }
    __syncthreads();
    for (int k = tid; k < NB; k += 256) {
        int c = he[k];
        be[k] = cb_e[k] + (c ? atomicAdd(&cur_e[k], c) : 0);
        int cn = hn[k];
        bn[k] = cb_n[k] + (cn ? atomicAdd(&cur_n[k], cn) : 0);
    }
    __syncthreads();
    #pragma unroll
    for (int k = 0; k < 13; k++) {
        int i = tid + k * 256;
        if (i < CHUNK) {
            int e = edge_idx[base + i], v = node_idx[base + i];
            int ke = pe[k] >> 12, oe = pe[k] & 4095;
            buf_e[be[ke] + oe] = (v << 6) | (e - ke * EB_E);
            int kn = pn[k] >> 12, on = pn[k] & 4095;
            buf_n[bn[kn] + on] = (e << 8) | (v - kn * EB_N);
        }
    }
}

// pass 2: per-bucket LDS counting sort -> PADDED CSR (rows 8-aligned, padded
// to multiple of 8 with zero-sentinel ids) + padded row starts rs + deg array.
__global__ __launch_bounds__(256) void bucket_sort_kernel(const int* __restrict__ buf_e,
                                                          const int* __restrict__ buf_n,
                                                          const int* __restrict__ cb_e,
                                                          const int* __restrict__ cb_n,
                                                          unsigned short* __restrict__ csr_e,
                                                          unsigned short* __restrict__ csr_n,
                                                          int* __restrict__ rs_e,
                                                          int* __restrict__ rs_n,
                                                          int* __restrict__ deg_e,
                                                          int* __restrict__ deg_n) {
    __shared__ int A[CAP];
    __shared__ int h[EB_N], bs[EB_N], cs[EB_N];
    int tid = threadIdx.x;
    bool edgeSide = blockIdx.x < NB;
    int k = edgeSide ? blockIdx.x : blockIdx.x - NB;
    int eb = edgeSide ? EB_E : EB_N;
    int shift = edgeSide ? 6 : 8;
    int mask = (1 << shift) - 1;
    int mp = edgeSide ? MP_E : MP_N;
    int sent = edgeSide ? N_NODES : N_EDGES;
    const int* cb  = edgeSide ? cb_e : cb_n;
    const int* buf = edgeSide ? buf_e : buf_n;
    unsigned short* csr = edgeSide ? csr_e : csr_n;
    int* rs  = edgeSide ? rs_e : rs_n;
    int* deg = edgeSide ? deg_e : deg_n;
    int base = cb[k];                               // exact base (buf reads)
    int base_pad = (base + k * mp + 7) & ~7;        // 8-aligned padded base (csr writes)
    int cnt = cb[k + 1] - base;
    for (int i = tid; i < eb; i += 256) h[i] = 0;
    __syncthreads();
    for (int i = tid; i < cnt; i += 256) {
        int it = buf[base + i];
        if (i < CAP) A[i] = it;
        atomicAdd(&h[it & mask], 1);
    }
    __syncthreads();
    if (tid == 0) {
        int s = 0;
        for (int j = 0; j < eb; j++) { bs[j] = s; s += (h[j] + 7) & ~7; }
    }
    __syncthreads();
    for (int j = tid; j < eb; j += 256) {
        rs[k * eb + j] = base_pad + bs[j];
        deg[k * eb + j] = h[j];
        cs[j] = h[j];
        h[j] = 0;
    }
    if (tid == 0 && k == NB - 1) rs[edgeSide ? N_EDGES : N_NODES] = NNZ;
    __syncthreads();
    // fill pad slots with sentinel (disjoint from scatter slots)
    for (int j = tid; j < eb; j += 256) {
        int c0 = cs[j], e0 = (c0 + 7) & ~7;
        for (int x = c0; x < e0; x++) csr[base_pad + bs[j] + x] = (unsigned short)sent;
    }
    for (int i = tid; i < cnt; i += 256) {
        int it = (i < CAP) ? A[i] : buf[base + i];
        int loc = it & mask;
        int off = bs[loc] + atomicAdd(&h[loc], 1);
        csr[base_pad + off] = (unsigned short)(it >> shift);
    }
}

// XCD-sliced edge aggregation (R8 proven structure), 16-lane-group-per-edge,
// UNCONDITIONAL chunk loop (rows 8-padded with sentinel): one uint4 csr load
// = 8 indices -> 8 unchecked table loads. Chunks round-robin across the
// group's 4 quads; 2-stage shfl reduce. Slice table 3.2MB, L2-resident/XCD.
__global__ __launch_bounds__(256) void edge_aggregate_kernel(const uint4* __restrict__ embh4,
                                                             const unsigned short* __restrict__ csr_e,
                                                             const int* __restrict__ rs_e,
                                                             const int* __restrict__ deg_e,
                                                             unsigned short* __restrict__ e_acc_h) {
    int sid = blockIdx.x & 7, g = blockIdx.x >> 3;
    const uint4* __restrict__ tbl = embh4 + (size_t)sid * 50001 * 4;
    const uint4* __restrict__ csr4 = (const uint4*)csr_e;
    int tid = threadIdx.x;
    int w = tid >> 6, lane = tid & 63;
    int grp = lane >> 4, q = (lane >> 2) & 3, c4 = lane & 3;
    int e = g * 16 + w * 4 + grp;                   // < MPAD always (628*16 = 10048)
    int s = rs_e[e];                                // pad rows: deg 0 -> loop skipped
    int dg = deg_e[e];
    int c0 = s >> 3, nc = (dg + 7) >> 3;
    float a[8] = {0.f, 0.f, 0.f, 0.f, 0.f, 0.f, 0.f, 0.f};
    for (int c = c0 + q; c < c0 + nc; c += 4) {
        uint4 pk = csr4[c];
        int ix[8];
        idx8(pk, ix);
        #pragma unroll
        for (int j = 0; j < 8; j++) acc_bf8(tbl[ix[j] * 4 + c4], a);
    }
    #pragma unroll
    for (int off = 4; off <= 8; off <<= 1) {
        #pragma unroll
        for (int jj = 0; jj < 8; jj++) a[jj] += __shfl_xor(a[jj], off);
    }
    if (q == 0) {
        uint4 o;
        o.x = f2bf(a[0]) | ((unsigned)f2bf(a[1]) << 16);
        o.y = f2bf(a[2]) | ((unsigned)f2bf(a[3]) << 16);
        o.z = f2bf(a[4]) | ((unsigned)f2bf(a[5]) << 16);
        o.w = f2bf(a[6]) | ((unsigned)f2bf(a[7]) << 16);
        ((uint4*)(e_acc_h + (size_t)e * C + sid * 32))[c4] = o;
    }
}

// e2[m][n] = Binv[m] * sum_k e_acc[m][k] * conv_w[n][k] via MFMA; grid (157,4)
// output stored SLICE-MAJOR [4][MPAD][64ch]; pad rows (m >= N_EDGES) ZERO
__global__ __launch_bounds__(256) void edge_gemm_mfma_kernel(const unsigned short* __restrict__ e_acc_h,
                                                             const unsigned short* __restrict__ cwh,
                                                             const int* __restrict__ deg_e,
                                                             unsigned short* __restrict__ e2h) {
    __shared__ __align__(16) unsigned short As[64 * 72];
    __shared__ __align__(16) unsigned short Bs[64 * 72];
    int i0 = blockIdx.x * 64, j0 = blockIdx.y * 64;
    int tid = threadIdx.x;
    int w = tid >> 6, lane = tid & 63;
    int col = lane & 15, quad = lane >> 4;
    floatx4 acc[4] = {};
    for (int step = 0; step < 4; step++) {
        int kb = step * 64;
        __syncthreads();
        #pragma unroll
        for (int l = 0; l < 2; l++) {
            int slot = tid + l * 256;
            int row = slot >> 3, grp = slot & 7;
            uint4 da = *(const uint4*)(e_acc_h + (size_t)(i0 + row) * C + kb + grp * 8);
            *(uint4*)(&As[row * 72 + grp * 8]) = da;
            uint4 db = *(const uint4*)(cwh + (size_t)(j0 + row) * C + kb + grp * 8);
            *(uint4*)(&Bs[row * 72 + grp * 8]) = db;
        }
        __syncthreads();
        #pragma unroll
        for (int sub = 0; sub < 2; sub++) {
            short8 a = *(const short8*)(&As[(w * 16 + col) * 72 + sub * 32 + quad * 8]);
            #pragma unroll
            for (int jt = 0; jt < 4; jt++) {
                short8 b = *(const short8*)(&Bs[(jt * 16 + col) * 72 + sub * 32 + quad * 8]);
                acc[jt] = __builtin_amdgcn_mfma_f32_16x16x32_bf16(a, b, acc[jt], 0, 0, 0);
            }
        }
    }
    #pragma unroll
    for (int r = 0; r < 4; r++) {
        int m = i0 + w * 16 + quad * 4 + r;          // < MPAD always
        int dg = deg_e[m];                           // pad rows: 0
        float binv = (dg > 0) ? 1.0f / (float)dg : 0.0f;
        #pragma unroll
        for (int jt = 0; jt < 4; jt++) {
            int ch = j0 + jt * 16 + col;
            e2h[(size_t)((ch >> 6) * MPAD + m) * 64 + (ch & 63)] = f2bf(acc[jt][r] * binv);
        }
    }
}

// XCD-sliced node aggregation, 64-CHANNEL slices (4 slices, table 1.28MB,
// L2-resident; sid = blockIdx&3 -> one slice per XCD): each 8-LANE group
// owns a node; 8 lanes cover one contiguous 128B row -> HALF the L2
// requests vs 32-ch slices. csr chunk load is wave-broadcast (1 load / 8
// incidences). Unconditional unpack (rows 8-padded). Fused Dinv/bias/lrelu;
// LDS transpose; 16B yT stores.
__global__ __launch_bounds__(256) void node_aggregate_t_kernel(const uint4* __restrict__ e2h4,
                                                               const unsigned short* __restrict__ csr_n,
                                                               const int* __restrict__ rs_n,
                                                               const int* __restrict__ deg_n,
                                                               const float* __restrict__ conv_b,
                                                               unsigned short* __restrict__ yT) {
    __shared__ unsigned short T[64][33];   // [slice-ch][node-local], stride 33
    int sid = blockIdx.x & 3, g = blockIdx.x >> 2;
    const uint4* __restrict__ csr4 = (const uint4*)csr_n;
    int tid = threadIdx.x;
    int group = tid >> 3, l8 = tid & 7;
    const uint4* __restrict__ tbl = e2h4 + (size_t)sid * MPAD * 8 + l8;
    int n = g * 32 + group;                         // < KTOT (1568*32 = 50176)
    int s = rs_n[min(n, N_NODES)];
    int dg = deg_n[n];
    int c0 = s >> 3, nc = (dg + 7) >> 3;
    float4 b0 = ((const float4*)conv_b)[sid * 16 + l8 * 2];
    float4 b1 = ((const float4*)conv_b)[sid * 16 + l8 * 2 + 1];
    float a[8] = {0.f, 0.f, 0.f, 0.f, 0.f, 0.f, 0.f, 0.f};
    for (int c = c0; c < c0 + nc; c++) {
        uint4 pk = csr4[c];                         // broadcast across the 8 lanes
        int ix[8];
        idx8(pk, ix);
        #pragma unroll
        for (int j = 0; j < 8; j++) acc_bf8(tbl[(size_t)ix[j] * 8], a);
    }
    float dinv = (dg > 0) ? 1.0f / (float)dg : 0.0f;
    float bb[8] = {b0.x, b0.y, b0.z, b0.w, b1.x, b1.y, b1.z, b1.w};
    #pragma unroll
    for (int jj = 0; jj < 8; jj++) {
        float r = a[jj] * dinv + bb[jj];
        r = (r > 0.f) ? r : SLOPE * r;
        if (n >= N_NODES) r = 0.f;                 // zero-pad rows for gram
        T[l8 * 8 + jj][group] = f2bf(r);
    }
    __syncthreads();
    int rr = tid >> 2, cc = tid & 3;               // 64 rows x 4 packers
    uint4 o;
    o.x = T[rr][cc * 8 + 0] | ((unsigned)T[rr][cc * 8 + 1] << 16);
    o.y = T[rr][cc * 8 + 2] | ((unsigned)T[rr][cc * 8 + 3] << 16);
    o.z = T[rr][cc * 8 + 4] | ((unsigned)T[rr][cc * 8 + 5] << 16);
    o.w = T[rr][cc * 8 + 6] | ((unsigned)T[rr][cc * 8 + 7] << 16);
    *(uint4*)(yT + (size_t)(sid * 64 + rr) * KTOT + g * 32 + cc * 8) = o;
}

// Gram partials via MFMA, symmetry-aware (10 upper-tri tile pairs), NO atomics.
__global__ __launch_bounds__(256) void gram_mfma_kernel(const unsigned short* __restrict__ yT,
                                                        float* __restrict__ part) {
    static const int PI[10] = {0, 0, 0, 0, 1, 1, 1, 2, 2, 3};
    static const int PJ[10] = {0, 1, 2, 3, 1, 2, 3, 2, 3, 3};
    __shared__ __align__(16) unsigned short As[64 * 72];  // [col][k], stride 72
    __shared__ __align__(16) unsigned short Bs[64 * 72];
    int i0 = PI[blockIdx.x] * 64, j0 = PJ[blockIdx.x] * 64;
    bool diag = (i0 == j0);
    int kb0 = blockIdx.y * KCHUNK;
    int tid = threadIdx.x;
    int w = tid >> 6, lane = tid & 63;
    int col = lane & 15, quad = lane >> 4;
    floatx4 acc[4] = {};
    for (int step = 0; step < KCHUNK / 64; step++) {
        int kb = kb0 + step * 64;
        __syncthreads();
        #pragma unroll
        for (int l = 0; l < 2; l++) {
            int slot = tid + l * 256;
            int row = slot >> 3, grp = slot & 7;
            uint4 da = *(const uint4*)(yT + (size_t)(i0 + row) * KTOT + kb + grp * 8);
            *(uint4*)(&As[row * 72 + grp * 8]) = da;
            if (!diag) {
                uint4 db = *(const uint4*)(yT + (size_t)(j0 + row) * KTOT + kb + grp * 8);
                *(uint4*)(&Bs[row * 72 + grp * 8]) = db;
            }
        }
        __syncthreads();
        const unsigned short* Bb = diag ? As : Bs;
        #pragma unroll
        for (int sub = 0; sub < 2; sub++) {
            short8 a = *(const short8*)(&As[(w * 16 + col) * 72 + sub * 32 + quad * 8]);
            #pragma unroll
            for (int jt = 0; jt < 4; jt++) {
                short8 b = *(const short8*)(&Bb[(jt * 16 + col) * 72 + sub * 32 + quad * 8]);
                acc[jt] = __builtin_amdgcn_mfma_f32_16x16x32_bf16(a, b, acc[jt], 0, 0, 0);
            }
        }
    }
    float* slab = part + ((size_t)blockIdx.y * 10 + blockIdx.x) * 4096;
    #pragma unroll
    for (int jt = 0; jt < 4; jt++)
        #pragma unroll
        for (int r = 0; r < 4; r++)
            slab[(w * 16 + quad * 4 + r) * 64 + jt * 16 + col] = acc[jt][r];
}

// FUSED: block i reduces g row i from the 98 partial slabs (with symmetric
// mirror) into LDS, then computes out row i = lrelu(g_row @ lin_w^T + lin_b).
__global__ __launch_bounds__(256) void greduce_out_kernel(const float* __restrict__ part,
                                                          const float* __restrict__ lin_w,
                                                          const float* __restrict__ lin_b,
                                                          float* __restrict__ out) {
    __shared__ float gs[C];
    int i = blockIdx.x, j = threadIdx.x;
    int a = i >> 6, b = j >> 6;
    int lo = min(a, b), hi = max(a, b);
    int t = lo * (7 - lo) / 2 + hi;          // pair index in PI/PJ order
    int li = (a <= b) ? (i & 63) : (j & 63);
    int lj = (a <= b) ? (j & 63) : (i & 63);
    const float* p = part + (size_t)t * 4096 + li * 64 + lj;
    float s = 0.f;
    for (int z = 0; z < NZB; z++) s += p[(size_t)z * 40960];
    gs[j] = s;
    __syncthreads();
    float acc = lin_b[j];
    const float* wrow = lin_w + (size_t)j * C;
    for (int k = 0; k < C; k++) acc += gs[k] * wrow[k];
    out[(size_t)i * C + j] = (acc > 0.f) ? acc : SLOPE * acc;
}

extern "C" void kernel_launch(void* const* d_in, const int* in_sizes, int n_in,
                              void* d_out, int out_size, void* d_ws, size_t ws_size,
                              hipStream_t stream) {
    const float* emb    = (const float*)d_in[0];
    const float* conv_w = (const float*)d_in[1];
    const float* conv_b = (const float*)d_in[2];
    const float* lin_w  = (const float*)d_in[3];
    const float* lin_b  = (const float*)d_in[4];
    const int*   eidx   = (const int*)d_in[5];
    const int* node_idx = eidx;        // edge_index[0]
    const int* edge_idx = eidx + NNZ;  // edge_index[1]

    char* ws = (char*)d_ws;
    int* cc_e  = (int*)(ws + OFF_CC_E);
    int* cc_n  = (int*)(ws + OFF_CC_N);
    int* cur_e = (int*)(ws + OFF_CUR_E);
    int* cur_n = (int*)(ws + OFF_CUR_N);
    int* deg_e = (int*)(ws + OFF_DEG_E);
    int* deg_n = (int*)(ws + OFF_DEG_N);
    int* cb_e  = (int*)(ws + OFF_CB_E);
    int* cb_n  = (int*)(ws + OFF_CB_N);
    int* rs_n  = (int*)(ws + OFF_RS_N);
    int* rs_e  = (int*)(ws + OFF_RS_E);
    int* buf_e = (int*)(ws + OFF_BUF_E);
    int* buf_n = (int*)(ws + OFF_BUF_N);
    unsigned short* csr_e = (unsigned short*)(ws + OFF_CSR_E);
    unsigned short* csr_n = (unsigned short*)(ws + OFF_CSR_N);
    uint4* embh4 = (uint4*)(ws + OFF_EMBH);
    unsigned short* e_acc_h = (unsigned short*)(ws + OFF_EACC);
    unsigned short* e2h = (unsigned short*)(ws + OFF_E2);
    unsigned short* cwh = (unsigned short*)(ws + OFF_CWH);
    unsigned short* yT  = (unsigned short*)(ws + OFF_YT);
    float* part = (float*)(ws + OFF_PART);
    float* out = (float*)d_out;

    zero_kernel<<<ZERO_BYTES / 4096, 256, 0, stream>>>((float4*)ws, ZERO_BYTES / 16);

    prep_kernel<<<PREP_EMB_BLOCKS + PREP_CW_BLOCKS + 256, 256, 0, stream>>>(
        (const float4*)emb, embh4, (const float4*)conv_w, (uint4*)cwh,
        node_idx, edge_idx, cc_e, cc_n);

    coarse_scan_kernel<<<1, 256, 0, stream>>>(cc_e, cc_n, cb_e, cb_n);

    bucket_scatter_kernel<<<256, 256, 0, stream>>>(node_idx, edge_idx, cb_e, cb_n,
                                                   cur_e, cur_n, buf_e, buf_n);

    bucket_sort_kernel<<<2 * NB, 256, 0, stream>>>(buf_e, buf_n, cb_e, cb_n,
                                                   csr_e, csr_n, rs_e, rs_n,
                                                   deg_e, deg_n);

    edge_aggregate_kernel<<<8 * EAGG_G, 256, 0, stream>>>(embh4, csr_e, rs_e, deg_e, e_acc_h);

    edge_gemm_mfma_kernel<<<dim3(MPAD / 64, C / 64), 256, 0, stream>>>(e_acc_h, cwh, deg_e, e2h);

    node_aggregate_t_kernel<<<4 * NAGG_G, 256, 0, stream>>>((const uint4*)e2h, csr_n, rs_n,
                                                            deg_n, conv_b, yT);

    gram_mfma_kernel<<<dim3(10, NZB), 256, 0, stream>>>(yT, part);

    greduce_out_kernel<<<C, 256, 0, stream>>>(part, lin_w, lin_b, out);
}